// Round 10
// baseline (183.126 us; speedup 1.0000x reference)
//
#include <hip/hip_runtime.h>

#define DEVINL __device__ __forceinline__

// 3-level a-trous B3-spline UWT, fused single kernel.
// Tile: 32x64 output, staged 64x92 rows (2..93), SW padded to 68 floats.
// pack p = tid&15 owns 4 consecutive cols (float4); ty = tid>>4 is the
// 16-lane DPP row-group id. Horizontal conv via DPP row_shr/row_shl.
//
// ROW-PAIR/QUAD TAP SHARING: strided structure (independent
// compile-time-offset ds_reads, good MLP — the rolling-window variant
// regressed by serializing reads), but each iteration produces ADJACENT
// rows so vertical taps overlap:
//   L0: pairs (r,r+1):   6 reads / 2 rows  (was 10)
//   L1: pairs (r,r+2):   6 reads / 2 rows  (same-parity, taps step 2)
//   L2: quads (r..r+12): 8 reads / 4 rows  (step 4; 16 quads = 1 iter exact)
// Per-block LDS items 22.7k -> 14.3k (-37%).
// LDS ping-pong A<->B, 2 x 96 x 68 x 4 = 52.2 KB -> 3 blocks/CU.

constexpr int W_IMG = 1024;
constexpr int H_IMG = 1024;
constexpr int TX = 32;                    // output cols per tile
constexpr int TY = 64;                    // output rows per tile (GYT exact)
constexpr int HALO = 16;                  // >= 2*(1+2+4)=14
constexpr int SW = 68;                    // LDS row STRIDE in floats (64 + 4 pad)
constexpr int SH = 96;                    // row slots (2..93 staged)
constexpr int GXT = W_IMG / TX;           // 32
constexpr int GYT = H_IMG / TY;           // 16 (exact)

constexpr float TP0 = 1.0f / 16.0f;
constexpr float TP1 = 1.0f / 4.0f;
constexpr float TP2 = 3.0f / 8.0f;

typedef float f32x4 __attribute__((ext_vector_type(4)));

// DPP cross-lane fetch within 16-lane rows. row_shr:n (0x110|n) = value from
// lane i-n; row_shl:n (0x100|n) = value from lane i+n. bound_ctrl=1 -> 0 at
// row edges. Corruption chain: L0 -> staged cols {0,1},{62,63}; L1 ->
// {0..5},{58..63}; L2 -> {0..13},{50..63}. Outputs use cols 16..47 (margin 2).
template <int CTRL>
DEVINL float dppf(float x) {
    return __int_as_float(__builtin_amdgcn_update_dpp(
        0, __float_as_int(x), CTRL, 0xF, 0xF, true));
}

DEVINL int reflx(int g) {
    g = g < 0 ? -g : g;
    return g >= W_IMG ? 2 * W_IMG - 2 - g : g;
}

DEVINL void nt_store4(float* p, float a, float b, float c, float d) {
    f32x4 t;
    t.x = a; t.y = b; t.z = c; t.w = d;
    __builtin_nontemporal_store(t, (f32x4*)p);
}

DEVINL float4 ld4(const float* p) { return *(const float4*)p; }

DEVINL float4 vert(const float4& a0, const float4& a1, const float4& a2,
                   const float4& a3, const float4& a4) {
    float4 v;
    v.x = TP0 * (a0.x + a4.x) + TP1 * (a1.x + a3.x) + TP2 * a2.x;
    v.y = TP0 * (a0.y + a4.y) + TP1 * (a1.y + a3.y) + TP2 * a2.y;
    v.z = TP0 * (a0.z + a4.z) + TP1 * (a1.z + a3.z) + TP2 * a2.z;
    v.w = TP0 * (a0.w + a4.w) + TP1 * (a1.w + a3.w) + TP2 * a2.w;
    return v;
}

template <int D>
DEVINL float4 horiz(const float4& v) {
    float4 u;
    if constexpr (D == 1) {
        const float am2 = dppf<0x111>(v.z);  // col-2 for comp0
        const float am1 = dppf<0x111>(v.w);  // col-1 for comp0
        const float ap1 = dppf<0x101>(v.x);  // col+1 for comp3
        const float ap2 = dppf<0x101>(v.y);  // col+2 for comp3
        u.x = TP0 * (am2 + v.z) + TP1 * (am1 + v.y) + TP2 * v.x;
        u.y = TP0 * (am1 + v.w) + TP1 * (v.x + v.z) + TP2 * v.y;
        u.z = TP0 * (v.x + ap1) + TP1 * (v.y + v.w) + TP2 * v.z;
        u.w = TP0 * (v.y + ap2) + TP1 * (v.z + ap1) + TP2 * v.w;
    } else if constexpr (D == 2) {
        u.x = TP0 * (dppf<0x111>(v.x) + dppf<0x101>(v.x)) +
              TP1 * (dppf<0x111>(v.z) + v.z) + TP2 * v.x;
        u.y = TP0 * (dppf<0x111>(v.y) + dppf<0x101>(v.y)) +
              TP1 * (dppf<0x111>(v.w) + v.w) + TP2 * v.y;
        u.z = TP0 * (dppf<0x111>(v.z) + dppf<0x101>(v.z)) +
              TP1 * (v.x + dppf<0x101>(v.x)) + TP2 * v.z;
        u.w = TP0 * (dppf<0x111>(v.w) + dppf<0x101>(v.w)) +
              TP1 * (v.y + dppf<0x101>(v.y)) + TP2 * v.w;
    } else {  // D == 4: same component, packs +/-1 and +/-2
        u.x = TP0 * (dppf<0x112>(v.x) + dppf<0x102>(v.x)) +
              TP1 * (dppf<0x111>(v.x) + dppf<0x101>(v.x)) + TP2 * v.x;
        u.y = TP0 * (dppf<0x112>(v.y) + dppf<0x102>(v.y)) +
              TP1 * (dppf<0x111>(v.y) + dppf<0x101>(v.y)) + TP2 * v.y;
        u.z = TP0 * (dppf<0x112>(v.z) + dppf<0x102>(v.z)) +
              TP1 * (dppf<0x111>(v.z) + dppf<0x101>(v.z)) + TP2 * v.z;
        u.w = TP0 * (dppf<0x112>(v.w) + dppf<0x102>(v.w)) +
              TP1 * (dppf<0x111>(v.w) + dppf<0x101>(v.w)) + TP2 * v.w;
    }
    return u;
}

// store w_LVL = center - u (and c_3 = u if ALSO_C) via hoisted per-thread base
template <int LVL, bool ALSO_C>
DEVINL void st(float* obase, bool pok, int ly, const float4& c,
               const float4& u) {
    if (pok && (unsigned)ly < (unsigned)TY) {
        constexpr size_t PL = (size_t)H_IMG * W_IMG;
        float* pw = obase + (size_t)LVL * PL + (size_t)ly * W_IMG;
        nt_store4(pw, c.x - u.x, c.y - u.y, c.z - u.z, c.w - u.w);
        if constexpr (ALSO_C) {
            float* pc = obase + (size_t)3 * PL + (size_t)ly * W_IMG;
            nt_store4(pc, u.x, u.y, u.z, u.w);
        }
    }
}

// L0 (D=1): 44 pairs (r, r+1), r = 4 + 2*pi. Output rows 4..91 exactly.
// Reads rows r-2..r+3 (6 independent b128s), all within staged 2..93.
DEVINL void level0(const float* src, float* dst, float* obase, bool pok,
                   int ty, int c4) {
#pragma unroll 2
    for (int k = 0; k < 3; ++k) {
        const int pi = ty + 16 * k;
        if (pi < 44) {  // uniform per 16-lane group
            const int r = 4 + 2 * pi;
            const float* b = &src[r * SW + c4];
            const float4 m2 = ld4(b - 2 * SW);
            const float4 m1 = ld4(b - 1 * SW);
            const float4 z0 = ld4(b);
            const float4 z1 = ld4(b + 1 * SW);
            const float4 z2 = ld4(b + 2 * SW);
            const float4 z3 = ld4(b + 3 * SW);
            const float4 u0 = horiz<1>(vert(m2, m1, z0, z1, z2));
            const float4 u1 = horiz<1>(vert(m1, z0, z1, z2, z3));
            st<0, false>(obase, pok, r - HALO, z0, u0);
            st<0, false>(obase, pok, r + 1 - HALO, z1, u1);
            *(float4*)&dst[r * SW + c4] = u0;
            *(float4*)&dst[(r + 1) * SW + c4] = u1;
        }
    }
}

// L1 (D=2): 40 same-parity pairs (r, r+2), r = 8 + (pi&1) + 4*(pi>>1).
// Covers rows 8..87 exactly. Reads rows r-4..r+6 step 2 (6 b128s), in 4..91.
DEVINL void level1(const float* src, float* dst, float* obase, bool pok,
                   int ty, int c4) {
#pragma unroll 2
    for (int k = 0; k < 3; ++k) {
        const int pi = ty + 16 * k;
        if (pi < 40) {
            const int r = 8 + (pi & 1) + 4 * (pi >> 1);
            const float* b = &src[r * SW + c4];
            const float4 m4 = ld4(b - 4 * SW);
            const float4 m2 = ld4(b - 2 * SW);
            const float4 z0 = ld4(b);
            const float4 z2 = ld4(b + 2 * SW);
            const float4 z4 = ld4(b + 4 * SW);
            const float4 z6 = ld4(b + 6 * SW);
            const float4 u0 = horiz<2>(vert(m4, m2, z0, z2, z4));
            const float4 u1 = horiz<2>(vert(m2, z0, z2, z4, z6));
            st<1, false>(obase, pok, r - HALO, z0, u0);
            st<1, false>(obase, pok, r + 2 - HALO, z2, u1);
            *(float4*)&dst[r * SW + c4] = u0;
            *(float4*)&dst[(r + 2) * SW + c4] = u1;
        }
    }
}

// L2 (D=4): 16 quads, one per ty, single iteration (no raggedness).
// Quad (c = ty&3, i = ty>>2): rows r0..r0+12 step 4 with r0 = 16+c+16i;
// covers rows 16..79 exactly. Reads rows r0-8..r0+20 step 4 (8 b128s),
// all within L1 output rows 8..87.
DEVINL void level2(const float* src, float* obase, bool pok, int ty, int c4) {
    const int r0 = 16 + (ty & 3) + 16 * (ty >> 2);
    const float* b = &src[r0 * SW + c4];
    const float4 q0 = ld4(b - 8 * SW);
    const float4 q1 = ld4(b - 4 * SW);
    const float4 q2 = ld4(b);
    const float4 q3 = ld4(b + 4 * SW);
    const float4 q4 = ld4(b + 8 * SW);
    const float4 q5 = ld4(b + 12 * SW);
    const float4 q6 = ld4(b + 16 * SW);
    const float4 q7 = ld4(b + 20 * SW);
    const float4 u0 = horiz<4>(vert(q0, q1, q2, q3, q4));
    const float4 u1 = horiz<4>(vert(q1, q2, q3, q4, q5));
    const float4 u2 = horiz<4>(vert(q2, q3, q4, q5, q6));
    const float4 u3 = horiz<4>(vert(q3, q4, q5, q6, q7));
    st<2, true>(obase, pok, r0 - HALO, q2, u0);
    st<2, true>(obase, pok, r0 + 4 - HALO, q3, u1);
    st<2, true>(obase, pok, r0 + 8 - HALO, q4, u2);
    st<2, true>(obase, pok, r0 + 12 - HALO, q5, u3);
}

__global__ __launch_bounds__(256, 3) void uwt3(const float* __restrict__ x,
                                               float* __restrict__ out) {
    __shared__ __align__(16) float A[SH * SW];  // 26112 B
    __shared__ __align__(16) float B[SH * SW];  // total 52224 B -> 3 blk/CU

    const int tid = threadIdx.x;
    const int p = tid & 15;
    const int ty = tid >> 4;
    int bid = blockIdx.x;
    const int bx = bid & 31;  bid >>= 5;      // GXT = 32 (pow2)
    const int by = bid & 15;                  // GYT = 16 (pow2)
    const int b = bid >> 4;
    const int oy0 = by * TY;
    const int gx0 = bx * TX;
    const float* xb = x + (size_t)b * (H_IMG * W_IMG);
    const int c4 = p * 4;
    const bool edge = (bx == 0) || (bx == GXT - 1);
    const bool pok = (p >= 4) && (p < 12);
    // hoisted per-thread output base (valid deref only when pok)
    float* obase = out + ((size_t)(b * 4) * H_IMG + oy0) * W_IMG +
                   (gx0 + c4 - HALO);

    // stage rows 2..93 only (L0's exact tap reach); 92 rows
#pragma unroll 2
    for (int k = 0; k < 6; ++k) {
        const int sr = 2 + ty + 16 * k;
        if (sr < 94) {
            int gy = oy0 - HALO + sr;
            gy = gy < 0 ? -gy : gy;
            if (gy >= H_IMG) gy = 2 * H_IMG - 2 - gy;
            const float* row = xb + (size_t)gy * W_IMG;
            const int gx = gx0 - HALO + c4;
            float4 v;
            if (!edge) {
                v = *(const float4*)(row + gx);
            } else {
                v.x = row[reflx(gx)];
                v.y = row[reflx(gx + 1)];
                v.z = row[reflx(gx + 2)];
                v.w = row[reflx(gx + 3)];
            }
            *(float4*)&A[sr * SW + c4] = v;
        }
    }
    __syncthreads();

    level0(A, B, obase, pok, ty, c4);   // B rows 4..91
    __syncthreads();
    level1(B, A, obase, pok, ty, c4);   // A rows 8..87
    __syncthreads();
    level2(A, obase, pok, ty, c4);
}

extern "C" void kernel_launch(void* const* d_in, const int* in_sizes, int n_in,
                              void* d_out, int out_size, void* d_ws,
                              size_t ws_size, hipStream_t stream) {
    const float* x = (const float*)d_in[0];
    float* out = (float*)d_out;
    const int nb = in_sizes[0] / (H_IMG * W_IMG);  // 8
    dim3 grid(nb * GYT * GXT);                     // 8*16*32 = 4096
    uwt3<<<grid, 256, 0, stream>>>(x, out);
}